// Round 18
// baseline (234.415 us; speedup 1.0000x reference)
//
#include <hip/hip_runtime.h>

typedef short   bf16x8 __attribute__((ext_vector_type(8)));
typedef unsigned short u16x8 __attribute__((ext_vector_type(8)));
typedef float   f32x4  __attribute__((ext_vector_type(4)));

constexpr int NSUB  = 8;
constexpr int NCODE = 256;
constexpr int SDIM  = 96;
constexpr int EMB   = NSUB * SDIM;          // 768
constexpr float C_SHIFT = 192.0f;   // harmless shift baked into c2 (cancels in gaps)
constexpr float THR = 0.02f;        // validated recheck trigger (rounds 2-3-7..10,14,17)

// 16x16 fragment packing: per m, 96 units of (64 lanes x 8 bf16) = 96 KB
constexpr int    CB_UNITS16    = 16 * 3 * 2;                      // tiles x ksteps x hi/lo
constexpr size_t WS_FRAG_BYTES = (size_t)NSUB * CB_UNITS16 * 64 * 16;  // 786432
constexpr size_t WS_NEEDED     = WS_FRAG_BYTES + (size_t)NSUB * NCODE * 4;

__device__ __forceinline__ unsigned short f2bf(float v) {
    unsigned u = __builtin_bit_cast(unsigned, v);
    u = u + 0x7FFFu + ((u >> 16) & 1u);          // RNE
    return (unsigned short)(u >> 16);
}
__device__ __forceinline__ float bf2f(unsigned short h) {
    unsigned u = ((unsigned)h) << 16;
    return __builtin_bit_cast(float, u);
}

// index-aware top-2 merge (validated in R13: passed absmax 0)
__device__ __forceinline__ void merge_top2(float& b1, int& i1, float& b2, int& i2,
                                           float ob1, int oi1, float ob2, int oi2) {
    bool o1_better = (ob1 < b1) || (ob1 == b1 && oi1 < i1);
    if (o1_better) {
        bool mine_better = (b1 < ob2) || (b1 == ob2 && i1 < oi2);
        if (mine_better) { b2 = b1; i2 = i1; } else { b2 = ob2; i2 = oi2; }
        b1 = ob1; i1 = oi1;
    } else {
        if ((ob1 < b2) || (ob1 == b2 && oi1 < i2)) { b2 = ob1; i2 = oi1; }
    }
}

// -------- pre-kernel: pack codebook into 16x16 A-fragments + c2 --------
// unit u = (t*3+ks)*2+h, lane l: code = t*16+(l&15), k = ks*32+(l>>4)*8+j,
// value = h==0 ? hi : lo of (-cb). wsc2 = 0.5*||c||^2 + C_SHIFT (fp64).
__global__ __launch_bounds__(256) void pq_prep16(const float* __restrict__ cb,
                                                 unsigned short* __restrict__ wsf,
                                                 float* __restrict__ wsc2)
{
    const int m   = (int)blockIdx.x;
    const int tid = (int)threadIdx.x;
    {
        const float* c = cb + ((size_t)m * NCODE + tid) * SDIM;
        double s = 0.0;
        for (int k = 0; k < SDIM; ++k) { double v = (double)c[k]; s += v * v; }
        wsc2[m * NCODE + tid] = (float)(0.5 * s + (double)C_SHIFT);
    }
    for (int i = 0; i < 24; ++i) {
        int idx = i * 256 + tid;        // [0, 6144) = unit*64 + lane
        int l   = idx & 63;
        int u   = idx >> 6;             // [0, 96)
        int h   = u & 1;
        int c6  = u >> 1;               // [0, 48)
        int ks  = c6 % 3;
        int t   = c6 / 3;
        int code = t * 16 + (l & 15);
        int k0   = ks * 32 + (l >> 4) * 8;
        const float* src = cb + (size_t)m * NCODE * SDIM + (size_t)code * SDIM + k0;
        u16x8 o;
        #pragma unroll
        for (int j = 0; j < 8; ++j) {
            float v = -src[j];
            unsigned short hb = f2bf(v);
            o[j] = (h == 0) ? hb : f2bf(v - bf2f(hb));
        }
        *(u16x8*)(wsf + ((size_t)m * 6144 + idx) * 8) = o;
    }
}

// ------ main: one wave owns (m, 16 rows); 16x16x32 MFMA, 16 serial tiles. ------
// ------ NO LDS/barriers; cb streamed from L2 ws; goal: VGPR <= 64 ->      ------
// ------ 8 waves/SIMD (64-reg allocation granule, m68/m69).                ------
__global__ __launch_bounds__(128) void pq_mfma16(
    const float* __restrict__ emb,
    const float* __restrict__ cb,
    const unsigned short* __restrict__ wsf,
    const float* __restrict__ wsc2,
    float* __restrict__ out,
    int nrows,
    int rowblks)
{
    const int tid  = (int)threadIdx.x;
    const int lane = tid & 63;
    const int g4   = lane >> 4;                  // 0..3
    const int m    = (int)blockIdx.x & 7;        // XCD-pinned subspace (R17)
    const int rb   = ((int)blockIdx.x >> 3) * 2 + (tid >> 6);
    if (rb >= rowblks) return;
    const int row0 = rb * 16;

    const unsigned short* wb = wsf + (size_t)m * 6144 * 8;
    const float* c2p = wsc2 + m * NCODE;

    // ---- x fragments (B operand): lane l = row row0+(l&15), dims ks*32+g4*8+j ----
    bf16x8 xh[3], xl[3];
    {
        int r = row0 + (lane & 15);
        if (r >= nrows) r = nrows - 1;
        const float* xr = emb + (size_t)r * EMB + m * SDIM + g4 * 8;
        #pragma unroll
        for (int ks = 0; ks < 3; ++ks) {
            float4 v0 = *(const float4*)(xr + ks * 32);
            float4 v1 = *(const float4*)(xr + ks * 32 + 4);
            float v[8] = { v0.x, v0.y, v0.z, v0.w, v1.x, v1.y, v1.z, v1.w };
            #pragma unroll
            for (int j = 0; j < 8; ++j) {
                unsigned short hb = f2bf(v[j]);
                xh[ks][j] = (short)hb;
                xl[ks][j] = (short)f2bf(v[j] - bf2f(hb));
            }
        }
    }

    // ---- 16 serial tiles: acc(4) init from c2, 9 MFMA, 4-element scan ----
    float b1 = 3.4e38f, b2 = 3.4e38f;
    int   i1 = 1 << 30, i2 = 1 << 30;
    #pragma unroll 1
    for (int t = 0; t < 16; ++t) {
        f32x4 a;
        {
            float4 q = *(const float4*)(c2p + t * 16 + g4 * 4);
            a[0] = q.x; a[1] = q.y; a[2] = q.z; a[3] = q.w;
        }
        const unsigned short* tb = wb + t * 3072 + lane * 8;
        #pragma unroll
        for (int ks = 0; ks < 3; ++ks) {
            bf16x8 ah = *(const bf16x8*)(tb + ks * 1024);
            bf16x8 al = *(const bf16x8*)(tb + ks * 1024 + 512);
            a = __builtin_amdgcn_mfma_f32_16x16x32_bf16(ah, xh[ks], a, 0, 0, 0);
            a = __builtin_amdgcn_mfma_f32_16x16x32_bf16(al, xh[ks], a, 0, 0, 0);
            a = __builtin_amdgcn_mfma_f32_16x16x32_bf16(ah, xl[ks], a, 0, 0, 0);
            __builtin_amdgcn_sched_barrier(0);   // cap frag liveness at 8 regs
        }
        // serial scan (per-lane ascending codes; first-min tie rule)
        const int kb = t * 16 + g4 * 4;          // C/D: code = t*16 + g4*4 + r
        #pragma unroll
        for (int r = 0; r < 4; ++r) {
            float sv = a[r];
            int   kv = kb + r;
            if (sv < b1)      { b2 = b1; i2 = i1; b1 = sv; i1 = kv; }
            else if (sv < b2) { b2 = sv; i2 = kv; }
        }
    }
    {   // merge lane^16 (same row, other code subset) — index-aware (validated)
        float ob1 = __shfl_xor(b1, 16);
        int   oi1 = __shfl_xor(i1, 16);
        float ob2 = __shfl_xor(b2, 16);
        int   oi2 = __shfl_xor(i2, 16);
        merge_top2(b1, i1, b2, i2, ob1, oi1, ob2, oi2);
    }
    {   // merge lane^32
        float ob1 = __shfl_xor(b1, 32);
        int   oi1 = __shfl_xor(i1, 32);
        float ob2 = __shfl_xor(b2, 32);
        int   oi2 = __shfl_xor(i2, 32);
        merge_top2(b1, i1, b2, i2, ob1, oi1, ob2, oi2);
    }

    // ---- cheap top-2 fp64 recheck (exact; validated THR; lane r owns row r) ----
    {
        int grow = row0 + (lane & 15);
        if (lane < 16 && grow < nrows && (b2 - b1 < THR)) {
            const float* xr = emb + (size_t)grow * EMB + m * SDIM;
            const float* ca = cb + ((size_t)m * NCODE + i1) * SDIM;
            const float* cbv = cb + ((size_t)m * NCODE + i2) * SDIM;
            double da = 0.0, db = 0.0;
            for (int kk = 0; kk < SDIM; ++kk) {
                double ea = (double)xr[kk] - (double)ca[kk];
                double eb = (double)xr[kk] - (double)cbv[kk];
                da += ea * ea; db += eb * eb;
            }
            if (db < da || (db == da && i2 < i1)) i1 = i2;
        }
    }

    // ---- gather + coalesced write-out (16 rows x 24 float4 = 384; 6 iters) ----
    #pragma unroll
    for (int ii = 0; ii < 6; ++ii) {
        int Q = ii * 64 + lane;                 // [0, 384)
        int r = Q / 24, f = Q % 24;
        int grow = row0 + r;
        int k = __shfl(i1, r);                  // lane r (<16) holds row r winner
        if (grow < nrows) {
            float4 v = *(const float4*)(cb + ((size_t)m * NCODE + k) * SDIM + f * 4);
            *(float4*)(out + (size_t)grow * EMB + m * SDIM + f * 4) = v;
        }
    }
}

// ---------------- fallback (round-2 kernel, validated) ----------------
__global__ __launch_bounds__(256) void pq_argmin_kernel(
    const float* __restrict__ emb, const float* __restrict__ cb,
    float* __restrict__ out, int nrows)
{
    const int m   = (int)(blockIdx.x & 7);
    const int row = (int)(blockIdx.x >> 3) * 256 + (int)threadIdx.x;
    const float* __restrict__ cbm = cb + (size_t)m * (NCODE * SDIM);
    __shared__ float half_c2[NCODE];
    {
        const int k = (int)threadIdx.x;
        const float* c = cbm + k * SDIM;
        float s = 0.f;
        #pragma unroll
        for (int i = 0; i < SDIM; i += 4) {
            const float4 v = *reinterpret_cast<const float4*>(c + i);
            s = fmaf(v.x, v.x, s); s = fmaf(v.y, v.y, s);
            s = fmaf(v.z, v.z, s); s = fmaf(v.w, v.w, s);
        }
        half_c2[k] = 0.5f * s;
    }
    __syncthreads();
    if (row >= nrows) return;
    float x[SDIM];
    {
        const float* xr = emb + (size_t)row * EMB + m * SDIM;
        #pragma unroll
        for (int i = 0; i < SDIM; i += 4) {
            const float4 v = *reinterpret_cast<const float4*>(xr + i);
            x[i+0] = v.x; x[i+1] = v.y; x[i+2] = v.z; x[i+3] = v.w;
        }
    }
    float best = 3.4e38f, best2 = 3.4e38f;
    int bestk = 0, bestk2 = 0;
    #pragma unroll 1
    for (int k = 0; k < NCODE; k += 4) {
        const float* c0 = cbm + (k + 0) * SDIM;
        const float* c1 = cbm + (k + 1) * SDIM;
        const float* c2 = cbm + (k + 2) * SDIM;
        const float* c3 = cbm + (k + 3) * SDIM;
        float a0 = 0.f, a1 = 0.f, a2 = 0.f, a3 = 0.f;
        #pragma unroll
        for (int i = 0; i < SDIM; i += 4) {
            const float4 v0 = *reinterpret_cast<const float4*>(c0 + i);
            const float4 v1 = *reinterpret_cast<const float4*>(c1 + i);
            const float4 v2 = *reinterpret_cast<const float4*>(c2 + i);
            const float4 v3 = *reinterpret_cast<const float4*>(c3 + i);
            a0 = fmaf(x[i+0], v0.x, a0); a0 = fmaf(x[i+1], v0.y, a0);
            a0 = fmaf(x[i+2], v0.z, a0); a0 = fmaf(x[i+3], v0.w, a0);
            a1 = fmaf(x[i+0], v1.x, a1); a1 = fmaf(x[i+1], v1.y, a1);
            a1 = fmaf(x[i+2], v1.z, a1); a1 = fmaf(x[i+3], v1.w, a1);
            a2 = fmaf(x[i+0], v2.x, a2); a2 = fmaf(x[i+1], v2.y, a2);
            a2 = fmaf(x[i+2], v2.z, a2); a2 = fmaf(x[i+3], v2.w, a2);
            a3 = fmaf(x[i+0], v3.x, a3); a3 = fmaf(x[i+1], v3.y, a3);
            a3 = fmaf(x[i+2], v3.z, a3); a3 = fmaf(x[i+3], v3.w, a3);
        }
        const float s[4] = { half_c2[k+0] - a0, half_c2[k+1] - a1,
                             half_c2[k+2] - a2, half_c2[k+3] - a3 };
        #pragma unroll
        for (int j = 0; j < 4; ++j) {
            if (s[j] < best)       { best2 = best; bestk2 = bestk; best = s[j]; bestk = k + j; }
            else if (s[j] < best2) { best2 = s[j]; bestk2 = k + j; }
        }
    }
    if (best2 - best < 0.02f) {
        const float* ca = cbm + bestk  * SDIM;
        const float* cbv = cbm + bestk2 * SDIM;
        double da = 0.0, db = 0.0;
        for (int i = 0; i < SDIM; ++i) {
            const double ea = (double)x[i] - (double)ca[i];
            const double eb = (double)x[i] - (double)cbv[i];
            da += ea * ea; db += eb * eb;
        }
        if (db < da || (db == da && bestk2 < bestk)) bestk = bestk2;
    }
    const float* cbest = cbm + bestk * SDIM;
    float* o = out + (size_t)row * EMB + m * SDIM;
    #pragma unroll
    for (int i = 0; i < SDIM; i += 4)
        *reinterpret_cast<float4*>(o + i) = *reinterpret_cast<const float4*>(cbest + i);
}

extern "C" void kernel_launch(void* const* d_in, const int* in_sizes, int n_in,
                              void* d_out, int out_size, void* d_ws, size_t ws_size,
                              hipStream_t stream) {
    const float* emb = (const float*)d_in[0];
    const float* cb  = (const float*)d_in[1];
    float* out = (float*)d_out;
    const int nrows = in_sizes[0] / EMB;    // 65536

    if (ws_size < WS_NEEDED) {
        const int rowBlocks = (nrows + 255) / 256;
        pq_argmin_kernel<<<dim3(rowBlocks * NSUB), dim3(256), 0, stream>>>(emb, cb, out, nrows);
        return;
    }

    unsigned short* wsf = (unsigned short*)d_ws;
    float* wsc2 = (float*)((char*)d_ws + WS_FRAG_BYTES);

    pq_prep16<<<dim3(NSUB), dim3(256), 0, stream>>>(cb, wsf, wsc2);

    const int rowblks = (nrows + 15) / 16;              // 4096
    const int nb      = ((rowblks + 1) / 2) * NSUB;     // 16384 blocks of 128
    pq_mfma16<<<dim3(nb), dim3(128), 0, stream>>>(emb, cb, wsf, wsc2, out, nrows, rowblks);
}

// Round 19
// 194.523 us; speedup vs baseline: 1.2051x; 1.2051x over previous
//
#include <hip/hip_runtime.h>

typedef _Float16 h8 __attribute__((ext_vector_type(8)));
typedef unsigned short u16x8 __attribute__((ext_vector_type(8)));
typedef float   f32x16 __attribute__((ext_vector_type(16)));

constexpr int NSUB  = 8;
constexpr int NCODE = 256;
constexpr int SDIM  = 96;
constexpr int EMB   = NSUB * SDIM;          // 768
constexpr float C_SHIFT = 192.0f;   // harmless shift baked into c2 (cancels in gaps)
constexpr float THR = 0.04f;        // fp16 1-pass: sigma~4e-3 worst ~5e-3; 8x margin

// fp16 fragment packing: per m, 48 units of (64 lanes x 8 f16) = 48 KB
constexpr size_t WS_FRAG_BYTES = (size_t)NSUB * 3072 * 16;       // 393216
constexpr size_t WS_NEEDED     = WS_FRAG_BYTES + (size_t)NSUB * NCODE * 4;

__device__ __forceinline__ unsigned short f2bf(float v) {
    unsigned u = __builtin_bit_cast(unsigned, v);
    u = u + 0x7FFFu + ((u >> 16) & 1u);          // RNE
    return (unsigned short)(u >> 16);
}

// -------- pre-kernel: pack codebook into fp16 32x32 A-fragments + c2 --------
// unit u = t*6+s, lane l: code = t*32+(l&31), k = s*16+(l>>5)*8+j, val = fp16(-c).
// wsc2 = 0.5*||c||^2 + C_SHIFT (fp64).
__global__ __launch_bounds__(256) void pq_prep_h(const float* __restrict__ cb,
                                                 unsigned short* __restrict__ wsf,
                                                 float* __restrict__ wsc2)
{
    const int m   = (int)blockIdx.x;
    const int tid = (int)threadIdx.x;
    {
        const float* c = cb + ((size_t)m * NCODE + tid) * SDIM;
        double s = 0.0;
        for (int k = 0; k < SDIM; ++k) { double v = (double)c[k]; s += v * v; }
        wsc2[m * NCODE + tid] = (float)(0.5 * s + (double)C_SHIFT);
    }
    for (int i = 0; i < 12; ++i) {
        int idx = i * 256 + tid;        // [0, 3072) = u*64 + l
        int l   = idx & 63;
        int u   = idx >> 6;             // [0, 48) = t*6 + s
        int s   = u % 6;
        int t   = u / 6;
        int code = t * 32 + (l & 31);
        int k0   = s * 16 + (l >> 5) * 8;
        const float* src = cb + (size_t)m * NCODE * SDIM + (size_t)code * SDIM + k0;
        u16x8 o;
        #pragma unroll
        for (int j = 0; j < 8; ++j) {
            _Float16 hv = (_Float16)(-src[j]);   // RNE
            o[j] = __builtin_bit_cast(unsigned short, hv);
        }
        *(u16x8*)(wsf + ((size_t)m * 3072 + idx) * 8) = o;
    }
}

// ------ main: one wave owns (m, 32 rows). NO LDS, NO barriers (R17 shape). ------
// ------ fp16 SINGLE-pass MFMA (48 loads, 48 MFMA, 24 x-regs) + top-3 scan  ------
// ------ + THR=0.04 exact fp64 top-3 recheck (guards fp16 error tail).      ------
__global__ __launch_bounds__(128) void pq_mfma17(
    const float* __restrict__ emb,
    const float* __restrict__ cb,
    const unsigned short* __restrict__ wsf,
    const float* __restrict__ wsc2,
    float* __restrict__ out,
    int nrows,
    int rowblks)
{
    const int tid  = (int)threadIdx.x;
    const int lane = tid & 63;
    const int hib  = lane >> 5;
    const int m    = (int)blockIdx.x & 7;               // XCD-pinned subspace
    const int rb   = ((int)blockIdx.x >> 3) * 2 + (tid >> 6);
    if (rb >= rowblks) return;
    const int row0 = rb * 32;

    const unsigned short* wb = wsf + (size_t)m * 3072 * 8;
    const float* c2p = wsc2 + m * NCODE;

    // ---- x fragments (B operand, fp16): lane l = row row0+(l&31), dims hib*8+s*16+j ----
    h8 xh[6];
    {
        int r = row0 + (lane & 31);
        if (r >= nrows) r = nrows - 1;
        const float* xr = emb + (size_t)r * EMB + m * SDIM + hib * 8;
        #pragma unroll
        for (int s = 0; s < 6; ++s) {
            float4 v0 = *(const float4*)(xr + s * 16);
            float4 v1 = *(const float4*)(xr + s * 16 + 4);
            float v[8] = { v0.x, v0.y, v0.z, v0.w, v1.x, v1.y, v1.z, v1.w };
            #pragma unroll
            for (int j = 0; j < 8; ++j) xh[s][j] = (_Float16)v[j];
        }
    }

    // ---- 4 t-pairs: acc init from c2, 12 MFMA, top-3 scan (code-ascending) ----
    float b1 = 3.4e38f, b2 = 3.4e38f, b3 = 3.4e38f;
    int   i1 = 1 << 30,  i2 = 1 << 30,  i3 = 1 << 30;
    #pragma unroll 1
    for (int p = 0; p < 4; ++p) {
        const int t0 = p * 2, t1 = t0 + 1;
        f32x16 a0, a1;
        #pragma unroll
        for (int rq = 0; rq < 4; ++rq) {
            float4 q0 = *(const float4*)(c2p + t0 * 32 + rq * 8 + hib * 4);
            float4 q1 = *(const float4*)(c2p + t1 * 32 + rq * 8 + hib * 4);
            a0[rq*4+0]=q0.x; a0[rq*4+1]=q0.y; a0[rq*4+2]=q0.z; a0[rq*4+3]=q0.w;
            a1[rq*4+0]=q1.x; a1[rq*4+1]=q1.y; a1[rq*4+2]=q1.z; a1[rq*4+3]=q1.w;
        }
        __builtin_amdgcn_s_setprio(1);
        #pragma unroll
        for (int s = 0; s < 6; ++s) {
            h8 c0 = *(const h8*)(wb + (size_t)((t0 * 6 + s) * 64 + lane) * 8);
            h8 c1 = *(const h8*)(wb + (size_t)((t1 * 6 + s) * 64 + lane) * 8);
            a0 = __builtin_amdgcn_mfma_f32_32x32x16_f16(c0, xh[s], a0, 0, 0, 0);
            a1 = __builtin_amdgcn_mfma_f32_32x32x16_f16(c1, xh[s], a1, 0, 0, 0);
        }
        __builtin_amdgcn_s_setprio(0);
        // top-3 serial scan, ascending code order per lane (first-min tie rule)
        #pragma unroll
        for (int r = 0; r < 16; ++r) {
            float sv = a0[r];
            int   kv = t0 * 32 + (r & 3) + 8 * (r >> 2) + hib * 4;
            if (sv < b1)      { b3 = b2; i3 = i2; b2 = b1; i2 = i1; b1 = sv; i1 = kv; }
            else if (sv < b2) { b3 = b2; i3 = i2; b2 = sv; i2 = kv; }
            else if (sv < b3) { b3 = sv; i3 = kv; }
        }
        #pragma unroll
        for (int r = 0; r < 16; ++r) {
            float sv = a1[r];
            int   kv = t1 * 32 + (r & 3) + 8 * (r >> 2) + hib * 4;
            if (sv < b1)      { b3 = b2; i3 = i2; b2 = b1; i2 = i1; b1 = sv; i1 = kv; }
            else if (sv < b2) { b3 = b2; i3 = i2; b2 = sv; i2 = kv; }
            else if (sv < b3) { b3 = sv; i3 = kv; }
        }
    }
    {   // merge lane^32 partner's sorted triple (index-aware: preserves tie rule)
        float ob1 = __shfl_xor(b1, 32), ob2 = __shfl_xor(b2, 32), ob3 = __shfl_xor(b3, 32);
        int   oi1 = __shfl_xor(i1, 32), oi2 = __shfl_xor(i2, 32), oi3 = __shfl_xor(i3, 32);
        auto ins = [&](float s, int i) {
            if (s < b1 || (s == b1 && i < i1))      { b3 = b2; i3 = i2; b2 = b1; i2 = i1; b1 = s; i1 = i; }
            else if (s < b2 || (s == b2 && i < i2)) { b3 = b2; i3 = i2; b2 = s; i2 = i; }
            else if (s < b3 || (s == b3 && i < i3)) { b3 = s; i3 = i; }
        };
        ins(ob1, oi1); ins(ob2, oi2); ins(ob3, oi3);
    }

    // ---- exact fp64 recheck of top-3 when gap12 < THR (covers fp16 error tail) ----
    {
        int grow = row0 + (lane & 31);
        if (lane < 32 && grow < nrows && (b2 - b1 < THR)) {
            int i3e = (b3 - b1 < THR) ? i3 : i1;
            const float* xr = emb + (size_t)grow * EMB + m * SDIM;
            const float* p1 = cb + ((size_t)m * NCODE + i1)  * SDIM;
            const float* p2 = cb + ((size_t)m * NCODE + i2)  * SDIM;
            const float* p3 = cb + ((size_t)m * NCODE + i3e) * SDIM;
            double d1 = 0.0, d2 = 0.0, d3 = 0.0;
            for (int kk = 0; kk < SDIM; ++kk) {
                double xv = (double)xr[kk];
                double e1 = xv - (double)p1[kk];
                double e2 = xv - (double)p2[kk];
                double e3 = xv - (double)p3[kk];
                d1 += e1 * e1; d2 += e2 * e2; d3 += e3 * e3;
            }
            double bd = d1; int bi = i1;
            if (d2 < bd || (d2 == bd && i2  < bi)) { bd = d2; bi = i2; }
            if (d3 < bd || (d3 == bd && i3e < bi)) { bd = d3; bi = i3e; }
            i1 = bi;
        }
    }

    // ---- gather + coalesced write-out (24 lanes = 384B runs per row) ----
    #pragma unroll
    for (int ii = 0; ii < 12; ++ii) {
        int Q = ii * 64 + lane;                 // 768 = 32 rows x 24 float4
        int r = Q / 24, f = Q % 24;
        int grow = row0 + r;
        int k = __shfl(i1, r);                  // winner held by lane r (<32)
        if (grow < nrows) {
            float4 v = *(const float4*)(cb + ((size_t)m * NCODE + k) * SDIM + f * 4);
            *(float4*)(out + (size_t)grow * EMB + m * SDIM + f * 4) = v;
        }
    }
}

// ---------------- fallback (round-2 kernel, validated) ----------------
__global__ __launch_bounds__(256) void pq_argmin_kernel(
    const float* __restrict__ emb, const float* __restrict__ cb,
    float* __restrict__ out, int nrows)
{
    const int m   = (int)(blockIdx.x & 7);
    const int row = (int)(blockIdx.x >> 3) * 256 + (int)threadIdx.x;
    const float* __restrict__ cbm = cb + (size_t)m * (NCODE * SDIM);
    __shared__ float half_c2[NCODE];
    {
        const int k = (int)threadIdx.x;
        const float* c = cbm + k * SDIM;
        float s = 0.f;
        #pragma unroll
        for (int i = 0; i < SDIM; i += 4) {
            const float4 v = *reinterpret_cast<const float4*>(c + i);
            s = fmaf(v.x, v.x, s); s = fmaf(v.y, v.y, s);
            s = fmaf(v.z, v.z, s); s = fmaf(v.w, v.w, s);
        }
        half_c2[k] = 0.5f * s;
    }
    __syncthreads();
    if (row >= nrows) return;
    float x[SDIM];
    {
        const float* xr = emb + (size_t)row * EMB + m * SDIM;
        #pragma unroll
        for (int i = 0; i < SDIM; i += 4) {
            const float4 v = *reinterpret_cast<const float4*>(xr + i);
            x[i+0] = v.x; x[i+1] = v.y; x[i+2] = v.z; x[i+3] = v.w;
        }
    }
    float best = 3.4e38f, best2 = 3.4e38f;
    int bestk = 0, bestk2 = 0;
    #pragma unroll 1
    for (int k = 0; k < NCODE; k += 4) {
        const float* c0 = cbm + (k + 0) * SDIM;
        const float* c1 = cbm + (k + 1) * SDIM;
        const float* c2 = cbm + (k + 2) * SDIM;
        const float* c3 = cbm + (k + 3) * SDIM;
        float a0 = 0.f, a1 = 0.f, a2 = 0.f, a3 = 0.f;
        #pragma unroll
        for (int i = 0; i < SDIM; i += 4) {
            const float4 v0 = *reinterpret_cast<const float4*>(c0 + i);
            const float4 v1 = *reinterpret_cast<const float4*>(c1 + i);
            const float4 v2 = *reinterpret_cast<const float4*>(c2 + i);
            const float4 v3 = *reinterpret_cast<const float4*>(c3 + i);
            a0 = fmaf(x[i+0], v0.x, a0); a0 = fmaf(x[i+1], v0.y, a0);
            a0 = fmaf(x[i+2], v0.z, a0); a0 = fmaf(x[i+3], v0.w, a0);
            a1 = fmaf(x[i+0], v1.x, a1); a1 = fmaf(x[i+1], v1.y, a1);
            a1 = fmaf(x[i+2], v1.z, a1); a1 = fmaf(x[i+3], v1.w, a1);
            a2 = fmaf(x[i+0], v2.x, a2); a2 = fmaf(x[i+1], v2.y, a2);
            a2 = fmaf(x[i+2], v2.z, a2); a2 = fmaf(x[i+3], v2.w, a2);
            a3 = fmaf(x[i+0], v3.x, a3); a3 = fmaf(x[i+1], v3.y, a3);
            a3 = fmaf(x[i+2], v3.z, a3); a3 = fmaf(x[i+3], v3.w, a3);
        }
        const float s[4] = { half_c2[k+0] - a0, half_c2[k+1] - a1,
                             half_c2[k+2] - a2, half_c2[k+3] - a3 };
        #pragma unroll
        for (int j = 0; j < 4; ++j) {
            if (s[j] < best)       { best2 = best; bestk2 = bestk; best = s[j]; bestk = k + j; }
            else if (s[j] < best2) { best2 = s[j]; bestk2 = k + j; }
        }
    }
    if (best2 - best < 0.02f) {
        const float* ca = cbm + bestk  * SDIM;
        const float* cbv = cbm + bestk2 * SDIM;
        double da = 0.0, db = 0.0;
        for (int i = 0; i < SDIM; ++i) {
            const double ea = (double)x[i] - (double)ca[i];
            const double eb = (double)x[i] - (double)cbv[i];
            da += ea * ea; db += eb * eb;
        }
        if (db < da || (db == da && bestk2 < bestk)) bestk = bestk2;
    }
    const float* cbest = cbm + bestk * SDIM;
    float* o = out + (size_t)row * EMB + m * SDIM;
    #pragma unroll
    for (int i = 0; i < SDIM; i += 4)
        *reinterpret_cast<float4*>(o + i) = *reinterpret_cast<const float4*>(cbest + i);
}

extern "C" void kernel_launch(void* const* d_in, const int* in_sizes, int n_in,
                              void* d_out, int out_size, void* d_ws, size_t ws_size,
                              hipStream_t stream) {
    const float* emb = (const float*)d_in[0];
    const float* cb  = (const float*)d_in[1];
    float* out = (float*)d_out;
    const int nrows = in_sizes[0] / EMB;    // 65536

    if (ws_size < WS_NEEDED) {
        const int rowBlocks = (nrows + 255) / 256;
        pq_argmin_kernel<<<dim3(rowBlocks * NSUB), dim3(256), 0, stream>>>(emb, cb, out, nrows);
        return;
    }

    unsigned short* wsf = (unsigned short*)d_ws;
    float* wsc2 = (float*)((char*)d_ws + WS_FRAG_BYTES);

    pq_prep_h<<<dim3(NSUB), dim3(256), 0, stream>>>(cb, wsf, wsc2);

    const int rowblks = (nrows + 31) / 32;              // 2048
    const int nb      = ((rowblks + 1) / 2) * NSUB;     // 8192 blocks of 128
    pq_mfma17<<<dim3(nb), dim3(128), 0, stream>>>(emb, cb, wsf, wsc2, out, nrows, rowblks);
}

// Round 21
// 192.445 us; speedup vs baseline: 1.2181x; 1.0108x over previous
//
#include <hip/hip_runtime.h>

typedef _Float16 h8 __attribute__((ext_vector_type(8)));
typedef unsigned short u16x8 __attribute__((ext_vector_type(8)));
typedef float   f32x16 __attribute__((ext_vector_type(16)));

constexpr int NSUB  = 8;
constexpr int NCODE = 256;
constexpr int SDIM  = 96;
constexpr int EMB   = NSUB * SDIM;          // 768
constexpr float C_SHIFT = 192.0f;   // harmless shift baked into c2 (cancels in gaps)
constexpr float THR = 0.04f;        // fp16 1-pass: sigma~4e-3 worst ~5e-3; 8x margin (R19-validated)

// fp16 fragment packing: per m, 48 units of (64 lanes x 8 f16) = 48 KB
constexpr size_t WS_FRAG_BYTES = (size_t)NSUB * 3072 * 16;       // 393216
constexpr size_t WS_NEEDED     = WS_FRAG_BYTES + (size_t)NSUB * NCODE * 4;

// -------- pre-kernel: pack codebook into fp16 32x32 A-fragments + c2 --------
// unit u = t*6+s, lane l: code = t*32+(l&31), k = s*16+(l>>5)*8+j, val = fp16(-c).
// wsc2 = 0.5*||c||^2 + C_SHIFT (fp64).
__global__ __launch_bounds__(256) void pq_prep_h(const float* __restrict__ cb,
                                                 unsigned short* __restrict__ wsf,
                                                 float* __restrict__ wsc2)
{
    const int m   = (int)blockIdx.x;
    const int tid = (int)threadIdx.x;
    {
        const float* c = cb + ((size_t)m * NCODE + tid) * SDIM;
        double s = 0.0;
        for (int k = 0; k < SDIM; ++k) { double v = (double)c[k]; s += v * v; }
        wsc2[m * NCODE + tid] = (float)(0.5 * s + (double)C_SHIFT);
    }
    for (int i = 0; i < 12; ++i) {
        int idx = i * 256 + tid;        // [0, 3072) = u*64 + l
        int l   = idx & 63;
        int u   = idx >> 6;             // [0, 48) = t*6 + s
        int s   = u % 6;
        int t   = u / 6;
        int code = t * 32 + (l & 31);
        int k0   = s * 16 + (l >> 5) * 8;
        const float* src = cb + (size_t)m * NCODE * SDIM + (size_t)code * SDIM + k0;
        u16x8 o;
        #pragma unroll
        for (int j = 0; j < 8; ++j) {
            _Float16 hv = (_Float16)(-src[j]);   // RNE
            o[j] = __builtin_bit_cast(unsigned short, hv);
        }
        *(u16x8*)(wsf + ((size_t)m * 3072 + idx) * 8) = o;
    }
}

// ------ main: one wave owns (m, 32 rows). NO LDS, NO barriers (R19 shape). ------
// ------ fp16 SINGLE-pass MFMA + float top-3 scan (exact, R19-validated)    ------
// ------ + THR=0.04 exact fp64 top-3 recheck with VECTORIZED float4 loads.  ------
__global__ __launch_bounds__(128) void pq_mfma19(
    const float* __restrict__ emb,
    const float* __restrict__ cb,
    const unsigned short* __restrict__ wsf,
    const float* __restrict__ wsc2,
    float* __restrict__ out,
    int nrows,
    int rowblks)
{
    const int tid  = (int)threadIdx.x;
    const int lane = tid & 63;
    const int hib  = lane >> 5;
    const int m    = (int)blockIdx.x & 7;               // XCD-pinned subspace
    const int rb   = ((int)blockIdx.x >> 3) * 2 + (tid >> 6);
    if (rb >= rowblks) return;
    const int row0 = rb * 32;

    const unsigned short* wb = wsf + (size_t)m * 3072 * 8;
    const float* c2p = wsc2 + m * NCODE;

    // ---- x fragments (B operand, fp16): lane l = row row0+(l&31), dims hib*8+s*16+j ----
    h8 xh[6];
    {
        int r = row0 + (lane & 31);
        if (r >= nrows) r = nrows - 1;
        const float* xr = emb + (size_t)r * EMB + m * SDIM + hib * 8;
        #pragma unroll
        for (int s = 0; s < 6; ++s) {
            float4 v0 = *(const float4*)(xr + s * 16);
            float4 v1 = *(const float4*)(xr + s * 16 + 4);
            float v[8] = { v0.x, v0.y, v0.z, v0.w, v1.x, v1.y, v1.z, v1.w };
            #pragma unroll
            for (int j = 0; j < 8; ++j) xh[s][j] = (_Float16)v[j];
        }
    }

    // ---- 4 t-pairs: acc init from c2, 12 MFMA, top-3 scan (code-ascending) ----
    float b1 = 3.4e38f, b2 = 3.4e38f, b3 = 3.4e38f;
    int   i1 = 1 << 30,  i2 = 1 << 30,  i3 = 1 << 30;
    #pragma unroll 1
    for (int p = 0; p < 4; ++p) {
        const int t0 = p * 2, t1 = t0 + 1;
        f32x16 a0, a1;
        #pragma unroll
        for (int rq = 0; rq < 4; ++rq) {
            float4 q0 = *(const float4*)(c2p + t0 * 32 + rq * 8 + hib * 4);
            float4 q1 = *(const float4*)(c2p + t1 * 32 + rq * 8 + hib * 4);
            a0[rq*4+0]=q0.x; a0[rq*4+1]=q0.y; a0[rq*4+2]=q0.z; a0[rq*4+3]=q0.w;
            a1[rq*4+0]=q1.x; a1[rq*4+1]=q1.y; a1[rq*4+2]=q1.z; a1[rq*4+3]=q1.w;
        }
        __builtin_amdgcn_s_setprio(1);
        #pragma unroll
        for (int s = 0; s < 6; ++s) {
            h8 c0 = *(const h8*)(wb + (size_t)((t0 * 6 + s) * 64 + lane) * 8);
            h8 c1 = *(const h8*)(wb + (size_t)((t1 * 6 + s) * 64 + lane) * 8);
            a0 = __builtin_amdgcn_mfma_f32_32x32x16_f16(c0, xh[s], a0, 0, 0, 0);
            a1 = __builtin_amdgcn_mfma_f32_32x32x16_f16(c1, xh[s], a1, 0, 0, 0);
        }
        __builtin_amdgcn_s_setprio(0);
        // top-3 serial scan, ascending code order per lane (first-min tie rule)
        #pragma unroll
        for (int r = 0; r < 16; ++r) {
            float sv = a0[r];
            int   kv = t0 * 32 + (r & 3) + 8 * (r >> 2) + hib * 4;
            if (sv < b1)      { b3 = b2; i3 = i2; b2 = b1; i2 = i1; b1 = sv; i1 = kv; }
            else if (sv < b2) { b3 = b2; i3 = i2; b2 = sv; i2 = kv; }
            else if (sv < b3) { b3 = sv; i3 = kv; }
        }
        #pragma unroll
        for (int r = 0; r < 16; ++r) {
            float sv = a1[r];
            int   kv = t1 * 32 + (r & 3) + 8 * (r >> 2) + hib * 4;
            if (sv < b1)      { b3 = b2; i3 = i2; b2 = b1; i2 = i1; b1 = sv; i1 = kv; }
            else if (sv < b2) { b3 = b2; i3 = i2; b2 = sv; i2 = kv; }
            else if (sv < b3) { b3 = sv; i3 = kv; }
        }
    }
    {   // merge lane^32 partner's sorted triple (index-aware: preserves tie rule)
        float ob1 = __shfl_xor(b1, 32), ob2 = __shfl_xor(b2, 32), ob3 = __shfl_xor(b3, 32);
        int   oi1 = __shfl_xor(i1, 32), oi2 = __shfl_xor(i2, 32), oi3 = __shfl_xor(i3, 32);
        auto ins = [&](float s, int i) {
            if (s < b1 || (s == b1 && i < i1))      { b3 = b2; i3 = i2; b2 = b1; i2 = i1; b1 = s; i1 = i; }
            else if (s < b2 || (s == b2 && i < i2)) { b3 = b2; i3 = i2; b2 = s; i2 = i; }
            else if (s < b3 || (s == b3 && i < i3)) { b3 = s; i3 = i; }
        };
        ins(ob1, oi1); ins(ob2, oi2); ins(ob3, oi3);
    }

    // ---- exact fp64 recheck of top-3 when gap12 < THR (float4-vectorized loads) ----
    {
        int grow = row0 + (lane & 31);
        if (lane < 32 && grow < nrows && (b2 - b1 < THR)) {
            int i3e = (b3 - b1 < THR) ? i3 : i1;
            const float* xr = emb + (size_t)grow * EMB + m * SDIM;
            const float* p1 = cb + ((size_t)m * NCODE + i1)  * SDIM;
            const float* p2 = cb + ((size_t)m * NCODE + i2)  * SDIM;
            const float* p3 = cb + ((size_t)m * NCODE + i3e) * SDIM;
            double d1 = 0.0, d2 = 0.0, d3 = 0.0;
            #pragma unroll 2
            for (int kk = 0; kk < SDIM; kk += 4) {
                float4 xv = *(const float4*)(xr + kk);
                float4 c1v = *(const float4*)(p1 + kk);
                float4 c2v = *(const float4*)(p2 + kk);
                float4 c3v = *(const float4*)(p3 + kk);
                double e;
                e = (double)xv.x - (double)c1v.x; d1 += e * e;
                e = (double)xv.y - (double)c1v.y; d1 += e * e;
                e = (double)xv.z - (double)c1v.z; d1 += e * e;
                e = (double)xv.w - (double)c1v.w; d1 += e * e;
                e = (double)xv.x - (double)c2v.x; d2 += e * e;
                e = (double)xv.y - (double)c2v.y; d2 += e * e;
                e = (double)xv.z - (double)c2v.z; d2 += e * e;
                e = (double)xv.w - (double)c2v.w; d2 += e * e;
                e = (double)xv.x - (double)c3v.x; d3 += e * e;
                e = (double)xv.y - (double)c3v.y; d3 += e * e;
                e = (double)xv.z - (double)c3v.z; d3 += e * e;
                e = (double)xv.w - (double)c3v.w; d3 += e * e;
            }
            double bd = d1; int bi = i1;
            if (d2 < bd || (d2 == bd && i2  < bi)) { bd = d2; bi = i2; }
            if (d3 < bd || (d3 == bd && i3e < bi)) { bd = d3; bi = i3e; }
            i1 = bi;
        }
    }

    // ---- gather + coalesced write-out (24 lanes = 384B runs per row) ----
    #pragma unroll
    for (int ii = 0; ii < 12; ++ii) {
        int Q = ii * 64 + lane;                 // 768 = 32 rows x 24 float4
        int r = Q / 24, f = Q % 24;
        int grow = row0 + r;
        int k = __shfl(i1, r);                  // winner held by lane r (<32)
        if (grow < nrows) {
            float4 v = *(const float4*)(cb + ((size_t)m * NCODE + k) * SDIM + f * 4);
            *(float4*)(out + (size_t)grow * EMB + m * SDIM + f * 4) = v;
        }
    }
}

// ---------------- fallback (round-2 kernel, validated) ----------------
__global__ __launch_bounds__(256) void pq_argmin_kernel(
    const float* __restrict__ emb, const float* __restrict__ cb,
    float* __restrict__ out, int nrows)
{
    const int m   = (int)(blockIdx.x & 7);
    const int row = (int)(blockIdx.x >> 3) * 256 + (int)threadIdx.x;
    const float* __restrict__ cbm = cb + (size_t)m * (NCODE * SDIM);
    __shared__ float half_c2[NCODE];
    {
        const int k = (int)threadIdx.x;
        const float* c = cbm + k * SDIM;
        float s = 0.f;
        #pragma unroll
        for (int i = 0; i < SDIM; i += 4) {
            const float4 v = *reinterpret_cast<const float4*>(c + i);
            s = fmaf(v.x, v.x, s); s = fmaf(v.y, v.y, s);
            s = fmaf(v.z, v.z, s); s = fmaf(v.w, v.w, s);
        }
        half_c2[k] = 0.5f * s;
    }
    __syncthreads();
    if (row >= nrows) return;
    float x[SDIM];
    {
        const float* xr = emb + (size_t)row * EMB + m * SDIM;
        #pragma unroll
        for (int i = 0; i < SDIM; i += 4) {
            const float4 v = *reinterpret_cast<const float4*>(xr + i);
            x[i+0] = v.x; x[i+1] = v.y; x[i+2] = v.z; x[i+3] = v.w;
        }
    }
    float best = 3.4e38f, best2 = 3.4e38f;
    int bestk = 0, bestk2 = 0;
    #pragma unroll 1
    for (int k = 0; k < NCODE; k += 4) {
        const float* c0 = cbm + (k + 0) * SDIM;
        const float* c1 = cbm + (k + 1) * SDIM;
        const float* c2 = cbm + (k + 2) * SDIM;
        const float* c3 = cbm + (k + 3) * SDIM;
        float a0 = 0.f, a1 = 0.f, a2 = 0.f, a3 = 0.f;
        #pragma unroll
        for (int i = 0; i < SDIM; i += 4) {
            const float4 v0 = *reinterpret_cast<const float4*>(c0 + i);
            const float4 v1 = *reinterpret_cast<const float4*>(c1 + i);
            const float4 v2 = *reinterpret_cast<const float4*>(c2 + i);
            const float4 v3 = *reinterpret_cast<const float4*>(c3 + i);
            a0 = fmaf(x[i+0], v0.x, a0); a0 = fmaf(x[i+1], v0.y, a0);
            a0 = fmaf(x[i+2], v0.z, a0); a0 = fmaf(x[i+3], v0.w, a0);
            a1 = fmaf(x[i+0], v1.x, a1); a1 = fmaf(x[i+1], v1.y, a1);
            a1 = fmaf(x[i+2], v1.z, a1); a1 = fmaf(x[i+3], v1.w, a1);
            a2 = fmaf(x[i+0], v2.x, a2); a2 = fmaf(x[i+1], v2.y, a2);
            a2 = fmaf(x[i+2], v2.z, a2); a2 = fmaf(x[i+3], v2.w, a2);
            a3 = fmaf(x[i+0], v3.x, a3); a3 = fmaf(x[i+1], v3.y, a3);
            a3 = fmaf(x[i+2], v3.z, a3); a3 = fmaf(x[i+3], v3.w, a3);
        }
        const float s[4] = { half_c2[k+0] - a0, half_c2[k+1] - a1,
                             half_c2[k+2] - a2, half_c2[k+3] - a3 };
        #pragma unroll
        for (int j = 0; j < 4; ++j) {
            if (s[j] < best)       { best2 = best; bestk2 = bestk; best = s[j]; bestk = k + j; }
            else if (s[j] < best2) { best2 = s[j]; bestk2 = k + j; }
        }
    }
    if (best2 - best < 0.02f) {
        const float* ca = cbm + bestk  * SDIM;
        const float* cbv = cbm + bestk2 * SDIM;
        double da = 0.0, db = 0.0;
        for (int i = 0; i < SDIM; ++i) {
            const double ea = (double)x[i] - (double)ca[i];
            const double eb = (double)x[i] - (double)cbv[i];
            da += ea * ea; db += eb * eb;
        }
        if (db < da || (db == da && bestk2 < bestk)) bestk = bestk2;
    }
    const float* cbest = cbm + bestk * SDIM;
    float* o = out + (size_t)row * EMB + m * SDIM;
    #pragma unroll
    for (int i = 0; i < SDIM; i += 4)
        *reinterpret_cast<float4*>(o + i) = *reinterpret_cast<const float4*>(cbest + i);
}

extern "C" void kernel_launch(void* const* d_in, const int* in_sizes, int n_in,
                              void* d_out, int out_size, void* d_ws, size_t ws_size,
                              hipStream_t stream) {
    const float* emb = (const float*)d_in[0];
    const float* cb  = (const float*)d_in[1];
    float* out = (float*)d_out;
    const int nrows = in_sizes[0] / EMB;    // 65536

    if (ws_size < WS_NEEDED) {
        const int rowBlocks = (nrows + 255) / 256;
        pq_argmin_kernel<<<dim3(rowBlocks * NSUB), dim3(256), 0, stream>>>(emb, cb, out, nrows);
        return;
    }

    unsigned short* wsf = (unsigned short*)d_ws;
    float* wsc2 = (float*)((char*)d_ws + WS_FRAG_BYTES);

    pq_prep_h<<<dim3(NSUB), dim3(256), 0, stream>>>(cb, wsf, wsc2);

    const int rowblks = (nrows + 31) / 32;              // 2048
    const int nb      = ((rowblks + 1) / 2) * NSUB;     // 8192 blocks of 128
    pq_mfma19<<<dim3(nb), dim3(128), 0, stream>>>(emb, cb, wsf, wsc2, out, nrows, rowblks);
}